// Round 1
// baseline (390.682 us; speedup 1.0000x reference)
//
#include <hip/hip_runtime.h>

#define HDIM 1024
#define BSZ  32
#define SLEN 2048

__device__ __forceinline__ float wave_reduce_sum(float v) {
    #pragma unroll
    for (int off = 32; off > 0; off >>= 1) v += __shfl_xor(v, off, 64);
    return v;
}

// K1: u[j] = sum_e v[e] * W[e, j],  j in [0, 2H). grid (8, 32) x 256
__global__ __launch_bounds__(256) void k_vtw(const float* __restrict__ W,
                                             const float* __restrict__ v,
                                             float* __restrict__ u) {
    const int j  = blockIdx.x * 256 + threadIdx.x;   // 0..2047
    const int e0 = blockIdx.y * 32;
    float acc = 0.f;
    #pragma unroll 8
    for (int e = 0; e < 32; ++e)
        acc += v[e0 + e] * W[(size_t)(e0 + e) * (2 * HDIM) + j];
    atomicAdd(&u[j], acc);
}

// K2: flash pass over encoder_outputs. grid (NCHUNK, B) x 256.
// Each block: batch b, rows [s0, s0+CHUNK). Stages 8 rows in LDS at a time,
// computes e_s = dot(row, u2) + c_b, online-softmax accumulates o.
__global__ __launch_bounds__(256) void k_flash(const float* __restrict__ enc,
                                               const float* __restrict__ u,
                                               const float* __restrict__ h,
                                               const float* __restrict__ bias,
                                               const float* __restrict__ v,
                                               float* __restrict__ e_out,
                                               float* __restrict__ m_out,
                                               float* __restrict__ z_out,
                                               float* __restrict__ o_out,
                                               int CHUNK, int NCHUNK) {
    __shared__ float stage[8 * HDIM];   // 32 KiB: 8 staged rows
    __shared__ float e8[8];
    __shared__ float red[256];
    __shared__ float cb_sh;

    const int t     = threadIdx.x;
    const int b     = blockIdx.y;
    const int chunk = blockIdx.x;
    const int s0    = chunk * CHUNK;
    const int wave  = t >> 6;
    const int lane  = t & 63;

    // c_b = dot(h_b, u[0:H]) + dot(bias, v)   (tiny, L2-resident)
    float part = 0.f;
    for (int i = t; i < HDIM; i += 256)
        part += h[b * HDIM + i] * u[i] + bias[i] * v[i];
    red[t] = part;
    __syncthreads();
    #pragma unroll
    for (int s = 128; s > 0; s >>= 1) {
        if (t < s) red[t] += red[t + s];
        __syncthreads();
    }
    if (t == 0) cb_sh = red[0];
    __syncthreads();
    const float c_b = cb_sh;
    const float* __restrict__ u2 = u + HDIM;

    float m_run = -3.4e38f;
    float z_run = 0.f;
    float4 o4 = make_float4(0.f, 0.f, 0.f, 0.f);

    const int nsub = CHUNK >> 3;   // subtiles of 8 rows
    for (int st = 0; st < nsub; ++st) {
        // ---- stage 8 rows (coalesced float4) ----
        const float4* __restrict__ g4 =
            reinterpret_cast<const float4*>(enc + ((size_t)b * SLEN + s0 + st * 8) * HDIM);
        float4* __restrict__ s4 = reinterpret_cast<float4*>(stage);
        #pragma unroll
        for (int k = 0; k < 8; ++k) s4[k * 256 + t] = g4[k * 256 + t];
        __syncthreads();

        // ---- dot: wave w handles rows w, w+4 ----
        for (int r = wave; r < 8; r += 4) {
            float acc = 0.f;
            #pragma unroll
            for (int seg = 0; seg < 4; ++seg) {
                const int hh = seg * 256 + lane * 4;
                float4 a  = *reinterpret_cast<const float4*>(stage + r * HDIM + hh);
                float4 uu = *reinterpret_cast<const float4*>(u2 + hh);
                acc += a.x * uu.x + a.y * uu.y + a.z * uu.z + a.w * uu.w;
            }
            acc = wave_reduce_sum(acc);
            if (lane == 0) {
                const float ev = acc + c_b;
                e8[r] = ev;
                e_out[(size_t)b * SLEN + s0 + st * 8 + r] = ev;
            }
        }
        __syncthreads();

        // ---- online softmax update (all threads, identical scalars) ----
        float ev[8];
        float msub = -3.4e38f;
        #pragma unroll
        for (int r = 0; r < 8; ++r) { ev[r] = e8[r]; msub = fmaxf(msub, ev[r]); }
        const float m_new = fmaxf(m_run, msub);
        const float resc  = __expf(m_run - m_new);   // first iter: exp(-inf)=0
        o4.x *= resc; o4.y *= resc; o4.z *= resc; o4.w *= resc;
        float psum = 0.f;
        #pragma unroll
        for (int r = 0; r < 8; ++r) {
            const float p = expf(ev[r] - m_new);
            psum += p;
            const float4 a = *reinterpret_cast<const float4*>(stage + r * HDIM + t * 4);
            o4.x += p * a.x; o4.y += p * a.y; o4.z += p * a.z; o4.w += p * a.w;
        }
        z_run = z_run * resc + psum;
        m_run = m_new;
        __syncthreads();   // done reading stage before next iteration overwrites
    }

    // ---- write partials ----
    float* optr = o_out + ((size_t)(b * NCHUNK + chunk)) * HDIM + t * 4;
    *reinterpret_cast<float4*>(optr) = o4;
    if (t == 0) {
        m_out[b * NCHUNK + chunk] = m_run;
        z_out[b * NCHUNK + chunk] = z_run;
    }
}

// K3: combine partials per batch; write context + attn_weights. grid B x 256.
__global__ __launch_bounds__(256) void k_combine(const float* __restrict__ e_in,
                                                 const float* __restrict__ m_in,
                                                 const float* __restrict__ z_in,
                                                 const float* __restrict__ o_in,
                                                 float* __restrict__ out,
                                                 int NCHUNK) {
    __shared__ float red[256];
    __shared__ float scale[64];
    const int t = threadIdx.x;
    const int b = blockIdx.x;

    float lm = -3.4e38f;
    if (t < NCHUNK) lm = m_in[b * NCHUNK + t];
    red[t] = lm;
    __syncthreads();
    #pragma unroll
    for (int s = 128; s > 0; s >>= 1) {
        if (t < s) red[t] = fmaxf(red[t], red[t + s]);
        __syncthreads();
    }
    const float M = red[0];
    __syncthreads();

    float lz = 0.f;
    if (t < NCHUNK) {
        const float sc = expf(m_in[b * NCHUNK + t] - M);
        scale[t] = sc;
        lz = sc * z_in[b * NCHUNK + t];
    }
    red[t] = lz;
    __syncthreads();
    #pragma unroll
    for (int s = 128; s > 0; s >>= 1) {
        if (t < s) red[t] += red[t + s];
        __syncthreads();
    }
    const float Z = red[0];
    const float invZ = 1.0f / Z;

    // context[b, 4t..4t+3]
    float4 acc = make_float4(0.f, 0.f, 0.f, 0.f);
    for (int c = 0; c < NCHUNK; ++c) {
        const float sc = scale[c];
        const float4 o4 = *reinterpret_cast<const float4*>(
            o_in + ((size_t)(b * NCHUNK + c)) * HDIM + t * 4);
        acc.x += sc * o4.x; acc.y += sc * o4.y; acc.z += sc * o4.z; acc.w += sc * o4.w;
    }
    acc.x *= invZ; acc.y *= invZ; acc.z *= invZ; acc.w *= invZ;
    *reinterpret_cast<float4*>(out + (size_t)b * HDIM + t * 4) = acc;

    // attn_weights[b, s] = exp(e - M) / Z
    float* wout = out + (size_t)BSZ * HDIM + (size_t)b * SLEN;
    const float* ein = e_in + (size_t)b * SLEN;
    for (int i = t; i < SLEN / 4; i += 256) {
        const float4 e4 = *reinterpret_cast<const float4*>(ein + i * 4);
        float4 w4;
        w4.x = expf(e4.x - M) * invZ;
        w4.y = expf(e4.y - M) * invZ;
        w4.z = expf(e4.z - M) * invZ;
        w4.w = expf(e4.w - M) * invZ;
        *reinterpret_cast<float4*>(wout + i * 4) = w4;
    }
}

extern "C" void kernel_launch(void* const* d_in, const int* in_sizes, int n_in,
                              void* d_out, int out_size, void* d_ws, size_t ws_size,
                              hipStream_t stream) {
    (void)in_sizes; (void)n_in; (void)out_size;
    const float* h    = (const float*)d_in[0];   // (1,B,H)
    const float* enc  = (const float*)d_in[1];   // (B,S,H)
    const float* W    = (const float*)d_in[2];   // (H,2H)
    const float* bias = (const float*)d_in[3];   // (H)
    const float* v    = (const float*)d_in[4];   // (H,1)
    float* out = (float*)d_out;

    // pick NCHUNK (s-chunks per batch) so workspace fits
    int NCHUNK = 64;
    while (NCHUNK > 1) {
        const size_t need = (size_t)(2 * HDIM + BSZ * SLEN + 2 * BSZ * NCHUNK
                                     + (size_t)BSZ * NCHUNK * HDIM + 64) * sizeof(float);
        if (need <= ws_size) break;
        NCHUNK >>= 1;
    }
    const int CHUNK = SLEN / NCHUNK;

    float* u    = (float*)d_ws;                  // 2H
    float* e_ws = u + 2 * HDIM;                  // B*S
    float* m_ws = e_ws + BSZ * SLEN;             // B*NCHUNK
    float* z_ws = m_ws + BSZ * NCHUNK;           // B*NCHUNK
    float* o_ws = z_ws + BSZ * NCHUNK;           // B*NCHUNK*H (16B aligned)

    hipMemsetAsync(u, 0, 2 * HDIM * sizeof(float), stream);
    dim3 g1(8, 32);
    k_vtw<<<g1, 256, 0, stream>>>(W, v, u);
    dim3 g2(NCHUNK, BSZ);
    k_flash<<<g2, 256, 0, stream>>>(enc, u, h, bias, v, e_ws, m_ws, z_ws, o_ws,
                                    CHUNK, NCHUNK);
    k_combine<<<BSZ, 256, 0, stream>>>(e_ws, m_ws, z_ws, o_ws, out, NCHUNK);
}